// Round 9
// baseline (458.319 us; speedup 1.0000x reference)
//
#include <hip/hip_runtime.h>
#include <stdint.h>

typedef unsigned long long u64;
typedef unsigned int u32;
typedef unsigned short u16;
typedef u32 u32x4 __attribute__((ext_vector_type(4)));
typedef float f32x4 __attribute__((ext_vector_type(4)));

// Fixed problem shape (N=100000, E=1600000, C_IN=C_OUT=128, NHEADS=4)
#define CIN 128
#define NN 100000
#define EE 1600000
#define CHUNK_LOG 11
#define CHUNK (1 << CHUNK_LOG)          // 2048 src nodes per chunk
#define NSLOT (CHUNK * 4)               // 8192 u64 slots = 64 KB LDS
#define NCHUNK ((NN + CHUNK - 1) >> CHUNK_LOG)   // 49

__device__ __forceinline__ float bf2f(u16 v) {
    union { u32 u; float f; } cv;
    cv.u = ((u32)v) << 16;
    return cv.f;
}

__device__ __forceinline__ u16 f2bf(float f) {      // RNE f32 -> bf16
    u32 b = __float_as_uint(f);
    return (u16)((b + 0x7FFFu + ((b >> 16) & 1u)) >> 16);
}

// Monotonic map: f32 -> u32 preserving total order. Never 0 for finite input.
__device__ __forceinline__ u32 mono32(float f) {
    u32 u = __float_as_uint(f);
    return ((int)u >= 0) ? (u | 0x80000000u) : ~u;
}

// ---------------------------------------------------------------------------
// k_s: (a) grid-stride zero of x_out region (nontemporal) and nm;
// (b) V table (W ⊗ att, f32) in LDS; (c) s-tables as bf16x4 per node.
__global__ __launch_bounds__(256) void k_s(const u16* __restrict__ x,
                                           const u16* __restrict__ W,
                                           const u16* __restrict__ att,
                                           ushort4* __restrict__ sjb,
                                           ushort4* __restrict__ sib,
                                           u32x4* __restrict__ xout16, int n_xout16,
                                           int* __restrict__ nm, int n_nodes) {
    int stride = gridDim.x * blockDim.x;
    int tid = blockIdx.x * blockDim.x + threadIdx.x;
    u32x4 z = { 0, 0, 0, 0 };
    for (int i = tid; i < n_xout16; i += stride) __builtin_nontemporal_store(z, &xout16[i]);
    for (int i = tid; i < n_nodes; i += stride) nm[i] = 0;

    // ---- V table in LDS (f32) ----
    __shared__ float Vl[1024];
    for (int slot = threadIdx.x; slot < 1024; slot += 256) {
        int k = slot >> 3, h8 = slot & 7;
        int head = h8 & 3;
        int off = (h8 < 4) ? 0 : 32;
        float acc = 0.0f;
        #pragma unroll
        for (int c = 0; c < 32; ++c)
            acc += bf2f(W[k * CIN + head * 32 + c]) * bf2f(att[head * 64 + off + c]);
        Vl[slot] = acc;
    }
    __syncthreads();

    for (int n = tid; n < n_nodes; n += stride) {
        const uint4* row = (const uint4*)(x + (size_t)n * CIN);
        float acc[8];
        #pragma unroll
        for (int h = 0; h < 8; ++h) acc[h] = 0.0f;
        #pragma unroll
        for (int q = 0; q < 16; ++q) {
            uint4 v = row[q];
            u32 w[4] = { v.x, v.y, v.z, v.w };
            #pragma unroll
            for (int j = 0; j < 4; ++j) {
                float x0 = bf2f((u16)(w[j] & 0xFFFFu));
                float x1 = bf2f((u16)(w[j] >> 16));
                int k0 = q * 8 + j * 2;
                #pragma unroll
                for (int h = 0; h < 8; ++h) acc[h] += x0 * Vl[k0 * 8 + h];
                #pragma unroll
                for (int h = 0; h < 8; ++h) acc[h] += x1 * Vl[(k0 + 1) * 8 + h];
            }
        }
        ushort4 a, b;
        a.x = f2bf(acc[0]); a.y = f2bf(acc[1]); a.z = f2bf(acc[2]); a.w = f2bf(acc[3]);
        b.x = f2bf(acc[4]); b.y = f2bf(acc[5]); b.z = f2bf(acc[6]); b.w = f2bf(acc[7]);
        sjb[n] = a;
        sib[n] = b;
    }
}

// ---------------------------------------------------------------------------
// LDS-resident segmented argmax: ZERO global atomics.
// Block (c, s): chunk c of src space, edge-segment s. Scans the src column of
// its segment (coalesced int4), filters src>>11==c, does LDS atomicMax of
// key=(mono32(alpha)<<32)|~e per head, then dumps the 64 KB table to a
// block-private global region (plain coalesced stores).
__global__ __launch_bounds__(256) void k_edge_lds(const int* __restrict__ ei,
                                                  const ushort4* __restrict__ sjb,
                                                  const ushort4* __restrict__ sib,
                                                  u64* __restrict__ segtab,
                                                  int n_edges, int S, int seglen) {
    __shared__ u64 tab[NSLOT];          // 64 KB
    for (int i = threadIdx.x; i < NSLOT; i += 256) tab[i] = 0ULL;
    __syncthreads();

    int c = blockIdx.x / S;
    int s = blockIdx.x - c * S;
    int lo = s * seglen;
    int cnt4 = seglen >> 2;
    const int4* src4 = (const int4*)(ei + lo);
    for (int i = threadIdx.x; i < cnt4; i += 256) {
        int4 sv = src4[i];
        int e0 = lo + (i << 2);
        int sa[4] = { sv.x, sv.y, sv.z, sv.w };
        #pragma unroll
        for (int j = 0; j < 4; ++j) {
            int src = sa[j];
            if ((src >> CHUNK_LOG) != c) continue;
            int e = e0 + j;
            int dst = ei[n_edges + e];
            ushort4 sj = sjb[src];
            ushort4 si = sib[dst];
            u64 lo64 = (u64)(u32)(~(u32)e);
            int slot = (src & (CHUNK - 1)) << 2;
            atomicMax(&tab[slot + 0], ((u64)mono32(bf2f(sj.x) + bf2f(si.x)) << 32) | lo64);
            atomicMax(&tab[slot + 1], ((u64)mono32(bf2f(sj.y) + bf2f(si.y)) << 32) | lo64);
            atomicMax(&tab[slot + 2], ((u64)mono32(bf2f(sj.z) + bf2f(si.z)) << 32) | lo64);
            atomicMax(&tab[slot + 3], ((u64)mono32(bf2f(sj.w) + bf2f(si.w)) << 32) | lo64);
        }
    }
    __syncthreads();

    u64* outp = segtab + (size_t)blockIdx.x * NSLOT;
    for (int i = threadIdx.x; i < NSLOT; i += 256)
        __builtin_nontemporal_store(tab[i], &outp[i]);
}

// ---------------------------------------------------------------------------
// Fold S copies per chunk; decode winning edge; set node_mask[dst].
__global__ void k_fold(const u64* __restrict__ segtab, const int* __restrict__ ei,
                       int* __restrict__ nm, int S, int n_slots_total, int n_edges) {
    int t = blockIdx.x * blockDim.x + threadIdx.x;
    if (t >= n_slots_total) return;
    int c = t >> (CHUNK_LOG + 2);
    int i = t & (NSLOT - 1);
    const u64* base = segtab + (size_t)c * S * NSLOT;
    u64 m = 0;
    for (int s = 0; s < S; ++s) {
        u64 v = base[(size_t)s * NSLOT + i];
        if (v > m) m = v;
    }
    if (m) {
        int e = (int)(~(u32)m);
        nm[ei[n_edges + e]] = 1;     // race-benign: all writers store 1
    }
}

// ---------------------------------------------------------------------------
// Fused epilogue: edge_keep (4 edges/thread, nontemporal f32x4) + node_mask
// f32 + batch_slices f32.
__global__ void k_final(const int* __restrict__ ei, const int* __restrict__ nm,
                        const int* __restrict__ slices, float* __restrict__ out,
                        int n_edges, int n_nodes, int ek_off, int nm_off, int sl_off) {
    int t = blockIdx.x * blockDim.x + threadIdx.x;
    int e0 = 4 * t;
    if (e0 < n_edges) {
        int4 srcs = ((const int4*)ei)[t];
        int4 dsts = ((const int4*)(ei + n_edges))[t];
        f32x4 v;
        v.x = (nm[srcs.x] & nm[dsts.x]) ? 1.0f : 0.0f;
        v.y = (nm[srcs.y] & nm[dsts.y]) ? 1.0f : 0.0f;
        v.z = (nm[srcs.z] & nm[dsts.z]) ? 1.0f : 0.0f;
        v.w = (nm[srcs.w] & nm[dsts.w]) ? 1.0f : 0.0f;
        __builtin_nontemporal_store(v, &((f32x4*)(out + ek_off))[t]);
    }
    if (t < n_nodes) out[nm_off + t] = nm[t] ? 1.0f : 0.0f;
    if (t < 2) out[sl_off + t] = (float)slices[t];   // 0 and 100000, exact
}

// ---------------------------------------------------------------------------
extern "C" void kernel_launch(void* const* d_in, const int* in_sizes, int n_in,
                              void* d_out, int out_size, void* d_ws, size_t ws_size,
                              hipStream_t stream) {
    // Bind inputs by UNIQUE flat size (permutation-proof):
    const u16* x = nullptr; const int* ei = nullptr; const int* sl = nullptr;
    const u16* W = nullptr; const u16* att = nullptr;
    for (int i = 0; i < n_in; ++i) {
        switch (in_sizes[i]) {
            case NN * CIN:   x   = (const u16*)d_in[i]; break;
            case 2 * EE:     ei  = (const int*)d_in[i]; break;
            case 2:          sl  = (const int*)d_in[i]; break;
            case CIN * CIN:  W   = (const u16*)d_in[i]; break;
            case 256:        att = (const u16*)d_in[i]; break;
            default: break;
        }
    }
    if (!x || !ei || !sl || !W || !att) return;

    float* out = (float*)d_out;             // f32 concat, return order
    const int N = NN;
    const int E = EE;

    // output layout (f32): [x_out N*128][edge_keep E][node_mask N][slices 2]
    const int ek_off = N * CIN;
    const int nm_off = ek_off + E;
    const int sl_off = nm_off + N;

    // workspace (16B-aligned): sjb N*8 | sib N*8 | nm N*4 | segtab
    char* ws = (char*)d_ws;
    ushort4* sjb = (ushort4*)(ws);
    ushort4* sib = (ushort4*)(ws + (size_t)N * 8);
    int*     nm  = (int*)    (ws + (size_t)N * 16);
    u64*  segtab = (u64*)    (ws + (size_t)N * 20);

    // Pick the largest edge-split S whose table copies fit the workspace.
    size_t base = (size_t)N * 20;
    int S = 1;
    for (int cand = 8; cand >= 1; cand >>= 1) {
        if (ws_size >= base + (size_t)NCHUNK * cand * NSLOT * 8) { S = cand; break; }
    }
    const int seglen = E / S;                    // E divisible by 1/2/4/8
    const int n_slots_total = NCHUNK * NSLOT;    // 401408
    const int n_xout16 = N * CIN / 4;            // u32x4 count, f32 x_out region

    k_s<<<1280, 256, 0, stream>>>(x, W, att, sjb, sib, (u32x4*)out, n_xout16, nm, N);
    k_edge_lds<<<NCHUNK * S, 256, 0, stream>>>(ei, sjb, sib, segtab, E, S, seglen);
    k_fold<<<(n_slots_total + 255) / 256, 256, 0, stream>>>(segtab, ei, nm, S, n_slots_total, E);
    k_final<<<(E / 4 + 255) / 256, 256, 0, stream>>>(ei, nm, sl, out, E, N, ek_off, nm_off, sl_off);
}

// Round 10
// 225.339 us; speedup vs baseline: 2.0339x; 2.0339x over previous
//
#include <hip/hip_runtime.h>
#include <stdint.h>

typedef unsigned long long u64;
typedef unsigned int u32;
typedef unsigned short u16;
typedef u32 u32x4 __attribute__((ext_vector_type(4)));
typedef float f32x4 __attribute__((ext_vector_type(4)));

// Fixed problem shape (N=100000, E=1600000, C_IN=C_OUT=128, NHEADS=4)
#define CIN 128
#define NN 100000
#define EE 1600000

__device__ __forceinline__ float bf2f(u16 v) {
    union { u32 u; float f; } cv;
    cv.u = ((u32)v) << 16;
    return cv.f;
}

__device__ __forceinline__ u16 f2bf(float f) {      // RNE f32 -> bf16
    u32 b = __float_as_uint(f);
    return (u16)((b + 0x7FFFu + ((b >> 16) & 1u)) >> 16);
}

// Monotonic map: f32 -> u32 preserving total order. Never 0 for finite input
// plus the |~e low word, so key==0 means "empty slot".
__device__ __forceinline__ u32 mono32(float f) {
    u32 u = __float_as_uint(f);
    return ((int)u >= 0) ? (u | 0x80000000u) : ~u;
}

// ---------------------------------------------------------------------------
// k_s: (a) grid-stride zero of x_out region (nontemporal), seg table, nm;
// (b) V table (W ⊗ att, f32) in LDS; (c) s-tables as bf16x4 per node.
__global__ __launch_bounds__(256) void k_s(const u16* __restrict__ x,
                                           const u16* __restrict__ W,
                                           const u16* __restrict__ att,
                                           ushort4* __restrict__ sjb,
                                           ushort4* __restrict__ sib,
                                           u32x4* __restrict__ xout16, int n_xout16,
                                           u32x4* __restrict__ seg16, int n_seg16,
                                           int* __restrict__ nm, int n_nodes) {
    int stride = gridDim.x * blockDim.x;
    int tid = blockIdx.x * blockDim.x + threadIdx.x;
    u32x4 z = { 0, 0, 0, 0 };
    for (int i = tid; i < n_xout16; i += stride) __builtin_nontemporal_store(z, &xout16[i]);
    for (int i = tid; i < n_seg16; i += stride) __builtin_nontemporal_store(z, &seg16[i]);
    for (int i = tid; i < n_nodes; i += stride) nm[i] = 0;

    // ---- V table in LDS (f32) ----
    __shared__ float Vl[1024];
    for (int slot = threadIdx.x; slot < 1024; slot += 256) {
        int k = slot >> 3, h8 = slot & 7;
        int head = h8 & 3;
        int off = (h8 < 4) ? 0 : 32;
        float acc = 0.0f;
        #pragma unroll
        for (int c = 0; c < 32; ++c)
            acc += bf2f(W[k * CIN + head * 32 + c]) * bf2f(att[head * 64 + off + c]);
        Vl[slot] = acc;
    }
    __syncthreads();

    for (int n = tid; n < n_nodes; n += stride) {
        const uint4* row = (const uint4*)(x + (size_t)n * CIN);
        float acc[8];
        #pragma unroll
        for (int h = 0; h < 8; ++h) acc[h] = 0.0f;
        #pragma unroll
        for (int q = 0; q < 16; ++q) {
            uint4 v = row[q];
            u32 w[4] = { v.x, v.y, v.z, v.w };
            #pragma unroll
            for (int j = 0; j < 4; ++j) {
                float x0 = bf2f((u16)(w[j] & 0xFFFFu));
                float x1 = bf2f((u16)(w[j] >> 16));
                int k0 = q * 8 + j * 2;
                #pragma unroll
                for (int h = 0; h < 8; ++h) acc[h] += x0 * Vl[k0 * 8 + h];
                #pragma unroll
                for (int h = 0; h < 8; ++h) acc[h] += x1 * Vl[(k0 + 1) * 8 + h];
            }
        }
        ushort4 a, b;
        a.x = f2bf(acc[0]); a.y = f2bf(acc[1]); a.z = f2bf(acc[2]); a.w = f2bf(acc[3]);
        b.x = f2bf(acc[4]); b.y = f2bf(acc[5]); b.z = f2bf(acc[6]); b.w = f2bf(acc[7]);
        sjb[n] = a;
        sib[n] = b;
    }
}

// ---------------------------------------------------------------------------
// Single-pass fused argmax on ONE shared table. key=(mono32(alpha)<<32)|~e:
// max score, tie -> min edge id. Test-then-atomic: with the full degree (~16)
// visible in one table, expected atomics/slot ~ H(16)=3.4 -> ~1.35M total
// (vs ~3M with 8 private copies). Stale test reads are only ever smaller ->
// at worst an extra atomic (correct). Device scope for cross-XCD atomicity.
__global__ __launch_bounds__(256) void k_edge(const int* __restrict__ ei,
                                              const ushort4* __restrict__ sjb,
                                              const ushort4* __restrict__ sib,
                                              u64* __restrict__ seg, int n_edges) {
    int e = blockIdx.x * blockDim.x + threadIdx.x;
    if (e >= n_edges) return;
    int src = ei[e], dst = ei[n_edges + e];
    ushort4 sj = sjb[src];
    ushort4 si = sib[dst];
    u64 lo = (u64)(u32)(~(u32)e);
    u64* slot = seg + (size_t)src * 4;
    ulonglong2 c01 = *(const ulonglong2*)(slot);
    ulonglong2 c23 = *(const ulonglong2*)(slot + 2);
    u64 k0 = ((u64)mono32(bf2f(sj.x) + bf2f(si.x)) << 32) | lo;
    u64 k1 = ((u64)mono32(bf2f(sj.y) + bf2f(si.y)) << 32) | lo;
    u64 k2 = ((u64)mono32(bf2f(sj.z) + bf2f(si.z)) << 32) | lo;
    u64 k3 = ((u64)mono32(bf2f(sj.w) + bf2f(si.w)) << 32) | lo;
    if (k0 > c01.x) atomicMax(&slot[0], k0);
    if (k1 > c01.y) atomicMax(&slot[1], k1);
    if (k2 > c23.x) atomicMax(&slot[2], k2);
    if (k3 > c23.y) atomicMax(&slot[3], k3);
}

// ---------------------------------------------------------------------------
// Decode winning edge per (src,head); set node_mask[dst].
__global__ void k_select(const int* __restrict__ ei, const u64* __restrict__ seg,
                         int* __restrict__ nm, int n4, int n_edges) {
    int t = blockIdx.x * blockDim.x + threadIdx.x;
    if (t >= n4) return;
    u64 m = seg[t];
    if (m) {
        int e = (int)(~(u32)m);
        nm[ei[n_edges + e]] = 1;     // race-benign: all writers store 1
    }
}

// ---------------------------------------------------------------------------
// Fused epilogue: edge_keep (4 edges/thread, nontemporal f32x4) + node_mask
// f32 + batch_slices f32.
__global__ void k_final(const int* __restrict__ ei, const int* __restrict__ nm,
                        const int* __restrict__ slices, float* __restrict__ out,
                        int n_edges, int n_nodes, int ek_off, int nm_off, int sl_off) {
    int t = blockIdx.x * blockDim.x + threadIdx.x;
    int e0 = 4 * t;
    if (e0 < n_edges) {
        int4 srcs = ((const int4*)ei)[t];
        int4 dsts = ((const int4*)(ei + n_edges))[t];
        f32x4 v;
        v.x = (nm[srcs.x] & nm[dsts.x]) ? 1.0f : 0.0f;
        v.y = (nm[srcs.y] & nm[dsts.y]) ? 1.0f : 0.0f;
        v.z = (nm[srcs.z] & nm[dsts.z]) ? 1.0f : 0.0f;
        v.w = (nm[srcs.w] & nm[dsts.w]) ? 1.0f : 0.0f;
        __builtin_nontemporal_store(v, &((f32x4*)(out + ek_off))[t]);
    }
    if (t < n_nodes) out[nm_off + t] = nm[t] ? 1.0f : 0.0f;
    if (t < 2) out[sl_off + t] = (float)slices[t];   // 0 and 100000, exact
}

// ---------------------------------------------------------------------------
extern "C" void kernel_launch(void* const* d_in, const int* in_sizes, int n_in,
                              void* d_out, int out_size, void* d_ws, size_t ws_size,
                              hipStream_t stream) {
    // Bind inputs by UNIQUE flat size (permutation-proof):
    const u16* x = nullptr; const int* ei = nullptr; const int* sl = nullptr;
    const u16* W = nullptr; const u16* att = nullptr;
    for (int i = 0; i < n_in; ++i) {
        switch (in_sizes[i]) {
            case NN * CIN:   x   = (const u16*)d_in[i]; break;
            case 2 * EE:     ei  = (const int*)d_in[i]; break;
            case 2:          sl  = (const int*)d_in[i]; break;
            case CIN * CIN:  W   = (const u16*)d_in[i]; break;
            case 256:        att = (const u16*)d_in[i]; break;
            default: break;
        }
    }
    if (!x || !ei || !sl || !W || !att) return;

    float* out = (float*)d_out;             // f32 concat, return order
    const int N = NN;
    const int E = EE;
    const int N4 = N * 4;

    // output layout (f32): [x_out N*128][edge_keep E][node_mask N][slices 2]
    const int ek_off = N * CIN;
    const int nm_off = ek_off + E;
    const int sl_off = nm_off + N;

    // workspace (16B-aligned): sjb N*8 | sib N*8 | nm N*4 | seg N4*8 (3.2MB)
    char* ws = (char*)d_ws;
    ushort4* sjb = (ushort4*)(ws);
    ushort4* sib = (ushort4*)(ws + (size_t)N * 8);
    int*     nm  = (int*)    (ws + (size_t)N * 16);
    u64*     seg = (u64*)    (ws + (size_t)N * 20);

    const int n_xout16 = N * CIN / 4;        // u32x4 count, f32 x_out region
    const int n_seg16  = N4 / 2;             // u32x4 count, seg table

    k_s<<<1280, 256, 0, stream>>>(x, W, att, sjb, sib,
                                  (u32x4*)out, n_xout16,
                                  (u32x4*)seg, n_seg16, nm, N);
    k_edge<<<(E + 255) / 256, 256, 0, stream>>>(ei, sjb, sib, seg, E);
    k_select<<<(N4 + 255) / 256, 256, 0, stream>>>(ei, seg, nm, N4, E);
    k_final<<<(E / 4 + 255) / 256, 256, 0, stream>>>(ei, nm, sl, out, E, N, ek_off, nm_off, sl_off);
}

// Round 11
// 204.124 us; speedup vs baseline: 2.2453x; 1.1039x over previous
//
#include <hip/hip_runtime.h>
#include <stdint.h>

typedef unsigned long long u64;
typedef unsigned int u32;
typedef unsigned short u16;
typedef u32 u32x4 __attribute__((ext_vector_type(4)));
typedef float f32x4 __attribute__((ext_vector_type(4)));

// Fixed problem shape (N=100000, E=1600000, C_IN=C_OUT=128, NHEADS=4)
#define CIN 128
#define NN 100000
#define EE 1600000

__device__ __forceinline__ float bf2f(u16 v) {
    union { u32 u; float f; } cv;
    cv.u = ((u32)v) << 16;
    return cv.f;
}

__device__ __forceinline__ u16 f2bf(float f) {      // RNE f32 -> bf16
    u32 b = __float_as_uint(f);
    return (u16)((b + 0x7FFFu + ((b >> 16) & 1u)) >> 16);
}

// Monotonic map: f32 -> u32 preserving total order. Never 0 for finite input
// plus the |~e low word, so key==0 means "empty slot".
__device__ __forceinline__ u32 mono32(float f) {
    u32 u = __float_as_uint(f);
    return ((int)u >= 0) ? (u | 0x80000000u) : ~u;
}

// ---------------------------------------------------------------------------
// k_s: (a) grid-stride zero of x_out region (nontemporal), seg table, nm;
// (b) V table (W ⊗ att, f32) in LDS; (c) s-tables as bf16x4 per node.
// __launch_bounds__(256,4) caps VGPR at 128 (r10 showed 256 VGPR -> 2
// waves/SIMD, latency-bound at 1.79 TB/s); unroll 4 keeps <=4 uint4 in
// flight. FMA order per node unchanged -> bit-identical s-tables.
__global__ __launch_bounds__(256, 4) void k_s(const u16* __restrict__ x,
                                              const u16* __restrict__ W,
                                              const u16* __restrict__ att,
                                              ushort4* __restrict__ sjb,
                                              ushort4* __restrict__ sib,
                                              u32x4* __restrict__ xout16, int n_xout16,
                                              u32x4* __restrict__ seg16, int n_seg16,
                                              int* __restrict__ nm, int n_nodes) {
    int stride = gridDim.x * blockDim.x;
    int tid = blockIdx.x * blockDim.x + threadIdx.x;
    u32x4 z = { 0, 0, 0, 0 };
    for (int i = tid; i < n_xout16; i += stride) __builtin_nontemporal_store(z, &xout16[i]);
    for (int i = tid; i < n_seg16; i += stride) __builtin_nontemporal_store(z, &seg16[i]);
    for (int i = tid; i < n_nodes; i += stride) nm[i] = 0;

    // ---- V table in LDS (f32) ----
    __shared__ float Vl[1024];
    for (int slot = threadIdx.x; slot < 1024; slot += 256) {
        int k = slot >> 3, h8 = slot & 7;
        int head = h8 & 3;
        int off = (h8 < 4) ? 0 : 32;
        float acc = 0.0f;
        #pragma unroll
        for (int c = 0; c < 32; ++c)
            acc += bf2f(W[k * CIN + head * 32 + c]) * bf2f(att[head * 64 + off + c]);
        Vl[slot] = acc;
    }
    __syncthreads();

    for (int n = tid; n < n_nodes; n += stride) {
        const uint4* row = (const uint4*)(x + (size_t)n * CIN);
        float acc[8];
        #pragma unroll
        for (int h = 0; h < 8; ++h) acc[h] = 0.0f;
        #pragma unroll 4
        for (int q = 0; q < 16; ++q) {
            uint4 v = row[q];
            u32 w[4] = { v.x, v.y, v.z, v.w };
            #pragma unroll
            for (int j = 0; j < 4; ++j) {
                float x0 = bf2f((u16)(w[j] & 0xFFFFu));
                float x1 = bf2f((u16)(w[j] >> 16));
                int k0 = q * 8 + j * 2;
                #pragma unroll
                for (int h = 0; h < 8; ++h) acc[h] += x0 * Vl[k0 * 8 + h];
                #pragma unroll
                for (int h = 0; h < 8; ++h) acc[h] += x1 * Vl[(k0 + 1) * 8 + h];
            }
        }
        ushort4 a, b;
        a.x = f2bf(acc[0]); a.y = f2bf(acc[1]); a.z = f2bf(acc[2]); a.w = f2bf(acc[3]);
        b.x = f2bf(acc[4]); b.y = f2bf(acc[5]); b.z = f2bf(acc[6]); b.w = f2bf(acc[7]);
        sjb[n] = a;
        sib[n] = b;
    }
}

// ---------------------------------------------------------------------------
// Single-pass fused argmax on ONE shared table. key=(mono32(alpha)<<32)|~e:
// max score, tie -> min edge id. Test-then-atomic with full degree (~16)
// visible -> ~H(16)=3.4 atomics/slot (~1.35M total; r10 WRITE 24 MB confirms).
// Stale test reads are only ever smaller -> extra atomic at worst (correct).
__global__ __launch_bounds__(256) void k_edge(const int* __restrict__ ei,
                                              const ushort4* __restrict__ sjb,
                                              const ushort4* __restrict__ sib,
                                              u64* __restrict__ seg, int n_edges) {
    int e = blockIdx.x * blockDim.x + threadIdx.x;
    if (e >= n_edges) return;
    int src = ei[e], dst = ei[n_edges + e];
    ushort4 sj = sjb[src];
    ushort4 si = sib[dst];
    u64 lo = (u64)(u32)(~(u32)e);
    u64* slot = seg + (size_t)src * 4;
    ulonglong2 c01 = *(const ulonglong2*)(slot);
    ulonglong2 c23 = *(const ulonglong2*)(slot + 2);
    u64 k0 = ((u64)mono32(bf2f(sj.x) + bf2f(si.x)) << 32) | lo;
    u64 k1 = ((u64)mono32(bf2f(sj.y) + bf2f(si.y)) << 32) | lo;
    u64 k2 = ((u64)mono32(bf2f(sj.z) + bf2f(si.z)) << 32) | lo;
    u64 k3 = ((u64)mono32(bf2f(sj.w) + bf2f(si.w)) << 32) | lo;
    if (k0 > c01.x) atomicMax(&slot[0], k0);
    if (k1 > c01.y) atomicMax(&slot[1], k1);
    if (k2 > c23.x) atomicMax(&slot[2], k2);
    if (k3 > c23.y) atomicMax(&slot[3], k3);
}

// ---------------------------------------------------------------------------
// Decode winning edge per (src,head); set node_mask[dst].
__global__ void k_select(const int* __restrict__ ei, const u64* __restrict__ seg,
                         int* __restrict__ nm, int n4, int n_edges) {
    int t = blockIdx.x * blockDim.x + threadIdx.x;
    if (t >= n4) return;
    u64 m = seg[t];
    if (m) {
        int e = (int)(~(u32)m);
        nm[ei[n_edges + e]] = 1;     // race-benign: all writers store 1
    }
}

// ---------------------------------------------------------------------------
// Fused epilogue: edge_keep (4 edges/thread, nontemporal f32x4) + node_mask
// f32 + batch_slices f32.
__global__ void k_final(const int* __restrict__ ei, const int* __restrict__ nm,
                        const int* __restrict__ slices, float* __restrict__ out,
                        int n_edges, int n_nodes, int ek_off, int nm_off, int sl_off) {
    int t = blockIdx.x * blockDim.x + threadIdx.x;
    int e0 = 4 * t;
    if (e0 < n_edges) {
        int4 srcs = ((const int4*)ei)[t];
        int4 dsts = ((const int4*)(ei + n_edges))[t];
        f32x4 v;
        v.x = (nm[srcs.x] & nm[dsts.x]) ? 1.0f : 0.0f;
        v.y = (nm[srcs.y] & nm[dsts.y]) ? 1.0f : 0.0f;
        v.z = (nm[srcs.z] & nm[dsts.z]) ? 1.0f : 0.0f;
        v.w = (nm[srcs.w] & nm[dsts.w]) ? 1.0f : 0.0f;
        __builtin_nontemporal_store(v, &((f32x4*)(out + ek_off))[t]);
    }
    if (t < n_nodes) out[nm_off + t] = nm[t] ? 1.0f : 0.0f;
    if (t < 2) out[sl_off + t] = (float)slices[t];   // 0 and 100000, exact
}

// ---------------------------------------------------------------------------
extern "C" void kernel_launch(void* const* d_in, const int* in_sizes, int n_in,
                              void* d_out, int out_size, void* d_ws, size_t ws_size,
                              hipStream_t stream) {
    // Bind inputs by UNIQUE flat size (permutation-proof):
    const u16* x = nullptr; const int* ei = nullptr; const int* sl = nullptr;
    const u16* W = nullptr; const u16* att = nullptr;
    for (int i = 0; i < n_in; ++i) {
        switch (in_sizes[i]) {
            case NN * CIN:   x   = (const u16*)d_in[i]; break;
            case 2 * EE:     ei  = (const int*)d_in[i]; break;
            case 2:          sl  = (const int*)d_in[i]; break;
            case CIN * CIN:  W   = (const u16*)d_in[i]; break;
            case 256:        att = (const u16*)d_in[i]; break;
            default: break;
        }
    }
    if (!x || !ei || !sl || !W || !att) return;

    float* out = (float*)d_out;             // f32 concat, return order
    const int N = NN;
    const int E = EE;
    const int N4 = N * 4;

    // output layout (f32): [x_out N*128][edge_keep E][node_mask N][slices 2]
    const int ek_off = N * CIN;
    const int nm_off = ek_off + E;
    const int sl_off = nm_off + N;

    // workspace (16B-aligned): sjb N*8 | sib N*8 | nm N*4 | seg N4*8 (3.2MB)
    char* ws = (char*)d_ws;
    ushort4* sjb = (ushort4*)(ws);
    ushort4* sib = (ushort4*)(ws + (size_t)N * 8);
    int*     nm  = (int*)    (ws + (size_t)N * 16);
    u64*     seg = (u64*)    (ws + (size_t)N * 20);

    const int n_xout16 = N * CIN / 4;        // u32x4 count, f32 x_out region
    const int n_seg16  = N4 / 2;             // u32x4 count, seg table

    k_s<<<1280, 256, 0, stream>>>(x, W, att, sjb, sib,
                                  (u32x4*)out, n_xout16,
                                  (u32x4*)seg, n_seg16, nm, N);
    k_edge<<<(E + 255) / 256, 256, 0, stream>>>(ei, sjb, sib, seg, E);
    k_select<<<(N4 + 255) / 256, 256, 0, stream>>>(ei, seg, nm, N4, E);
    k_final<<<(E / 4 + 255) / 256, 256, 0, stream>>>(ei, nm, sl, out, E, N, ek_off, nm_off, sl_off);
}